// Round 4
// baseline (7444.897 us; speedup 1.0000x reference)
//
#include <hip/hip_runtime.h>
#include <math.h>

#define N_NODES 100000
#define N_EDGES 3200000
#define NFEAT 512
#define NHID 256
#define NCLASS 16
#define NLAYERS 8
#define TM 32                    // nodes per fused-layer block (100000 = 3125*32 exactly)

#define SCAN_CHUNK 1024
#define NB ((N_NODES + SCAN_CHUNK - 1) / SCAN_CHUNK)   // 98

typedef float vf4 __attribute__((ext_vector_type(4)));

// ---------------- CSR build ----------------
__global__ void k_hist(const int* __restrict__ dst, int* __restrict__ cnt) {
  int i = blockIdx.x * 256 + threadIdx.x;
  if (i < N_EDGES) atomicAdd(&cnt[dst[i]], 1);
}

__global__ void k_blocksum(const int* __restrict__ cnt, int* __restrict__ bs) {
  __shared__ int red[256];
  int b = blockIdx.x, t = threadIdx.x;
  int s = 0;
  int base = b * SCAN_CHUNK;
  for (int j = 0; j < 4; ++j) {
    int i = base + t + j * 256;
    if (i < N_NODES) s += cnt[i];
  }
  red[t] = s;
  __syncthreads();
  for (int off = 128; off > 0; off >>= 1) {
    if (t < off) red[t] += red[t + off];
    __syncthreads();
  }
  if (t == 0) bs[b] = red[0];
}

__global__ void k_scan_top(int* __restrict__ bs, int* __restrict__ rp) {
  if (threadIdx.x == 0) {
    int run = 0;
    for (int b = 0; b < NB; ++b) { int v = bs[b]; bs[b] = run; run += v; }
    rp[N_NODES] = run;
  }
}

__global__ void k_scan_write(const int* __restrict__ cnt, const int* __restrict__ bs,
                             int* __restrict__ rp) {
  __shared__ int tot[256];
  int b = blockIdx.x, t = threadIdx.x;
  int base = b * SCAN_CHUNK + t * 4;
  int v0 = 0, v1 = 0, v2 = 0, v3 = 0;
  if (base + 0 < N_NODES) v0 = cnt[base + 0];
  if (base + 1 < N_NODES) v1 = cnt[base + 1];
  if (base + 2 < N_NODES) v2 = cnt[base + 2];
  if (base + 3 < N_NODES) v3 = cnt[base + 3];
  int tsum = v0 + v1 + v2 + v3;
  tot[t] = tsum;
  __syncthreads();
  for (int off = 1; off < 256; off <<= 1) {
    int v = 0;
    if (t >= off) v = tot[t - off];
    __syncthreads();
    if (t >= off) tot[t] += v;
    __syncthreads();
  }
  int excl = tot[t] - tsum + bs[b];
  if (base + 0 < N_NODES) rp[base + 0] = excl;
  if (base + 1 < N_NODES) rp[base + 1] = excl + v0;
  if (base + 2 < N_NODES) rp[base + 2] = excl + v0 + v1;
  if (base + 3 < N_NODES) rp[base + 3] = excl + v0 + v1 + v2;
}

__global__ void k_fill(const int* __restrict__ src, const int* __restrict__ dst,
                       const float* __restrict__ w, const int* __restrict__ rp,
                       int* __restrict__ fill, int* __restrict__ col,
                       float* __restrict__ val) {
  int i = blockIdx.x * 256 + threadIdx.x;
  if (i < N_EDGES) {
    int d = dst[i];
    int pos = rp[d] + atomicAdd(&fill[d], 1);
    col[pos] = src[i];
    val[pos] = w[i];
  }
}

// ---------------- fused layer: SpMM -> LDS -> GEMM -> epilogue ----------------
// Block: 128 threads, TM=32 nodes, all 256 output cols.
// Phase 1: gather sup = 0.9*sum(w*h[src]) + 0.1*h0 into supT[feat][node] (LDS).
//          (h0 read non-temporal: streams, doesn't evict gather-hot h from L3.)
// Phase 2: C = supT^T @ W via BK=16 LDS-staged W chunks; conflict-free reads
//          (a: broadcast b128; b: Bs[k][4tx+64q], 16x16B contiguous = free).
// Epilogue: out = relu(theta*C + (1-theta)*sup + h)  -> nt store to OTHER h buffer
//          (double-buffered: other blocks still gather from h; in-place would race).
__global__ __launch_bounds__(128)
void k_layer(const int* __restrict__ rp, const int* __restrict__ col,
             const float* __restrict__ val, const float* __restrict__ h,
             const float* __restrict__ h0, const float* __restrict__ W,
             float* __restrict__ out, float theta) {
  __shared__ float supT[256][36];   // [feat][node], stride 36 floats (16B-aligned rows)
  __shared__ float Bs[16][256];     // W chunk          total LDS = 52 KB -> 3 blocks/CU
  int tid = threadIdx.x;
  int node0 = blockIdx.x * TM;

  // ---- phase 1: gather ----
  {
    int wv = tid >> 6, lane = tid & 63;   // wave owns 16 nodes; lane owns feats 4l..4l+3
    const float4* __restrict__ h4 = (const float4*)h;
    for (int i = 0; i < 16; ++i) {
      int nl = wv * 16 + i;
      int n = node0 + nl;
      int e0 = rp[n], e1 = rp[n + 1];
      float4 a0 = make_float4(0.f, 0.f, 0.f, 0.f);
      float4 a1 = make_float4(0.f, 0.f, 0.f, 0.f);
      int e = e0;
      for (; e + 8 <= e1; e += 8) {
        int   s0 = col[e],     s1 = col[e + 1], s2 = col[e + 2], s3 = col[e + 3];
        int   s4 = col[e + 4], s5 = col[e + 5], s6 = col[e + 6], s7 = col[e + 7];
        float w0 = val[e],     w1 = val[e + 1], w2 = val[e + 2], w3 = val[e + 3];
        float w4 = val[e + 4], w5 = val[e + 5], w6 = val[e + 6], w7 = val[e + 7];
        float4 v0 = h4[(size_t)s0 * 64 + lane];
        float4 v1 = h4[(size_t)s1 * 64 + lane];
        float4 v2 = h4[(size_t)s2 * 64 + lane];
        float4 v3 = h4[(size_t)s3 * 64 + lane];
        float4 v4 = h4[(size_t)s4 * 64 + lane];
        float4 v5 = h4[(size_t)s5 * 64 + lane];
        float4 v6 = h4[(size_t)s6 * 64 + lane];
        float4 v7 = h4[(size_t)s7 * 64 + lane];
        a0.x += w0 * v0.x; a0.y += w0 * v0.y; a0.z += w0 * v0.z; a0.w += w0 * v0.w;
        a1.x += w1 * v1.x; a1.y += w1 * v1.y; a1.z += w1 * v1.z; a1.w += w1 * v1.w;
        a0.x += w2 * v2.x; a0.y += w2 * v2.y; a0.z += w2 * v2.z; a0.w += w2 * v2.w;
        a1.x += w3 * v3.x; a1.y += w3 * v3.y; a1.z += w3 * v3.z; a1.w += w3 * v3.w;
        a0.x += w4 * v4.x; a0.y += w4 * v4.y; a0.z += w4 * v4.z; a0.w += w4 * v4.w;
        a1.x += w5 * v5.x; a1.y += w5 * v5.y; a1.z += w5 * v5.z; a1.w += w5 * v5.w;
        a0.x += w6 * v6.x; a0.y += w6 * v6.y; a0.z += w6 * v6.z; a0.w += w6 * v6.w;
        a1.x += w7 * v7.x; a1.y += w7 * v7.y; a1.z += w7 * v7.z; a1.w += w7 * v7.w;
      }
      for (; e < e1; ++e) {
        int s0 = col[e];
        float w0 = val[e];
        float4 v0 = h4[(size_t)s0 * 64 + lane];
        a0.x += w0 * v0.x; a0.y += w0 * v0.y; a0.z += w0 * v0.z; a0.w += w0 * v0.w;
      }
      vf4 z = __builtin_nontemporal_load((const vf4*)h0 + (size_t)n * 64 + lane);
      supT[4 * lane + 0][nl] = 0.9f * (a0.x + a1.x) + 0.1f * z.x;
      supT[4 * lane + 1][nl] = 0.9f * (a0.y + a1.y) + 0.1f * z.y;
      supT[4 * lane + 2][nl] = 0.9f * (a0.z + a1.z) + 0.1f * z.z;
      supT[4 * lane + 3][nl] = 0.9f * (a0.w + a1.w) + 0.1f * z.w;
    }
  }
  __syncthreads();

  // ---- phase 2: C[32][256] = supT^T @ W ----
  int tx = tid & 15;   // cols {4tx..4tx+3} + 64q
  int ty = tid >> 4;   // rows ty*4..ty*4+3
  float acc[4][16];
#pragma unroll
  for (int i = 0; i < 4; ++i)
#pragma unroll
    for (int j = 0; j < 16; ++j) acc[i][j] = 0.f;

  for (int kc = 0; kc < NHID; kc += 16) {
    const float4* __restrict__ Wv = (const float4*)(W + (size_t)kc * 256);
    float4* Bv = (float4*)&Bs[0][0];
#pragma unroll
    for (int j = 0; j < 8; ++j) Bv[tid + j * 128] = Wv[tid + j * 128];
    __syncthreads();
#pragma unroll
    for (int k = 0; k < 16; ++k) {
      float a_[4], b_[16];
      *(float4*)&a_[0]  = *(const float4*)&supT[kc + k][ty * 4];
      *(float4*)&b_[0]  = *(const float4*)&Bs[k][tx * 4];
      *(float4*)&b_[4]  = *(const float4*)&Bs[k][tx * 4 + 64];
      *(float4*)&b_[8]  = *(const float4*)&Bs[k][tx * 4 + 128];
      *(float4*)&b_[12] = *(const float4*)&Bs[k][tx * 4 + 192];
#pragma unroll
      for (int i = 0; i < 4; ++i)
#pragma unroll
        for (int j = 0; j < 16; ++j) acc[i][j] += a_[i] * b_[j];
    }
    __syncthreads();
  }

  // ---- epilogue ----
  float omt = 1.f - theta;
#pragma unroll
  for (int i = 0; i < 4; ++i) {
    int r = ty * 4 + i;
    int gm = node0 + r;
    const float* __restrict__ hrow = &h[(size_t)gm * 256];
#pragma unroll
    for (int q = 0; q < 4; ++q) {
      int c = tx * 4 + 64 * q;
      float4 hv = *(const float4*)&hrow[c];
      float s0 = supT[c + 0][r], s1 = supT[c + 1][r];
      float s2 = supT[c + 2][r], s3 = supT[c + 3][r];
      vf4 o;
      o.x = fmaxf(theta * acc[i][4 * q + 0] + omt * s0 + hv.x, 0.f);
      o.y = fmaxf(theta * acc[i][4 * q + 1] + omt * s1 + hv.y, 0.f);
      o.z = fmaxf(theta * acc[i][4 * q + 2] + omt * s2 + hv.z, 0.f);
      o.w = fmaxf(theta * acc[i][4 * q + 3] + omt * s3 + hv.w, 0.f);
      __builtin_nontemporal_store(o, (vf4*)&out[(size_t)gm * 256 + c]);
    }
  }
}

// ---------------- layer-0 GEMM: out1 = out2 = relu(x@w0 + b0) ----------------
// 128x128 tile, BK=16, 8x8 micro-tile with split cols (4tx / 64+4tx):
// b-reads are 16x16B contiguous -> conflict-free (round-3: 3.5e7 conflicts @ tx*8).
__global__ __launch_bounds__(256)
void k_gemm0(const float* __restrict__ A, const float* __restrict__ W,
             const float* __restrict__ bias, float* __restrict__ out1,
             float* __restrict__ out2) {
  __shared__ float As[16][128];
  __shared__ float Bs[16][128];
  int bm = blockIdx.x * 128, bn = blockIdx.y * 128;
  int tid = threadIdx.x;
  int tx = tid & 15, ty = tid >> 4;
  float acc[8][8];
#pragma unroll
  for (int i = 0; i < 8; ++i)
#pragma unroll
    for (int j = 0; j < 8; ++j) acc[i][j] = 0.f;

  for (int kc = 0; kc < NFEAT; kc += 16) {
#pragma unroll
    for (int it = 0; it < 2; ++it) {
      int idx = tid + it * 256;
      int m = idx >> 2, q = (idx & 3) * 4;
      int gm = bm + m;
      float4 f = make_float4(0.f, 0.f, 0.f, 0.f);
      if (gm < N_NODES) f = *(const float4*)&A[(size_t)gm * NFEAT + kc + q];
      As[q + 0][m] = f.x; As[q + 1][m] = f.y; As[q + 2][m] = f.z; As[q + 3][m] = f.w;
    }
#pragma unroll
    for (int it = 0; it < 2; ++it) {
      int idx = tid + it * 256;
      int kk = idx >> 5, nq = (idx & 31) * 4;
      *(float4*)&Bs[kk][nq] = *(const float4*)&W[(size_t)(kc + kk) * NHID + bn + nq];
    }
    __syncthreads();
#pragma unroll
    for (int k = 0; k < 16; ++k) {
      float a[8], b[8];
      *(float4*)&a[0] = *(const float4*)&As[k][ty * 8];
      *(float4*)&a[4] = *(const float4*)&As[k][ty * 8 + 4];
      *(float4*)&b[0] = *(const float4*)&Bs[k][tx * 4];
      *(float4*)&b[4] = *(const float4*)&Bs[k][tx * 4 + 64];
#pragma unroll
      for (int i = 0; i < 8; ++i)
#pragma unroll
        for (int j = 0; j < 8; ++j) acc[i][j] += a[i] * b[j];
    }
    __syncthreads();
  }

  int c0 = bn + tx * 4, c1 = bn + 64 + tx * 4;
#pragma unroll
  for (int i = 0; i < 8; ++i) {
    int gm = bm + ty * 8 + i;
    if (gm >= N_NODES) continue;
    float4 o0, o1;
    o0.x = fmaxf(acc[i][0] + bias[c0 + 0], 0.f);
    o0.y = fmaxf(acc[i][1] + bias[c0 + 1], 0.f);
    o0.z = fmaxf(acc[i][2] + bias[c0 + 2], 0.f);
    o0.w = fmaxf(acc[i][3] + bias[c0 + 3], 0.f);
    o1.x = fmaxf(acc[i][4] + bias[c1 + 0], 0.f);
    o1.y = fmaxf(acc[i][5] + bias[c1 + 1], 0.f);
    o1.z = fmaxf(acc[i][6] + bias[c1 + 2], 0.f);
    o1.w = fmaxf(acc[i][7] + bias[c1 + 3], 0.f);
    *(float4*)&out1[(size_t)gm * NHID + c0] = o0;
    *(float4*)&out1[(size_t)gm * NHID + c1] = o1;
    *(float4*)&out2[(size_t)gm * NHID + c0] = o0;
    *(float4*)&out2[(size_t)gm * NHID + c1] = o1;
  }
}

// ---------------- head: out = sigmoid(h @ w1 + b1) ----------------
__global__ __launch_bounds__(256)
void k_final(const float* __restrict__ h, const float* __restrict__ w1,
             const float* __restrict__ b1, float* __restrict__ out) {
  __shared__ float ws[NHID * NCLASS];
  int t = threadIdx.x;
  for (int i = t; i < NHID * NCLASS; i += 256) ws[i] = w1[i];
  __syncthreads();
  int node = blockIdx.x * 16 + (t >> 4);
  int c = t & 15;
  if (node >= N_NODES) return;
  float acc = b1[c];
  const float* hr = &h[(size_t)node * NHID];
  for (int k = 0; k < NHID; k += 4) {
    float4 hv = *(const float4*)&hr[k];
    acc += hv.x * ws[(k + 0) * NCLASS + c];
    acc += hv.y * ws[(k + 1) * NCLASS + c];
    acc += hv.z * ws[(k + 2) * NCLASS + c];
    acc += hv.w * ws[(k + 3) * NCLASS + c];
  }
  out[(size_t)node * NCLASS + c] = 1.f / (1.f + __expf(-acc));
}

// ---------------- host ----------------
extern "C" void kernel_launch(void* const* d_in, const int* in_sizes, int n_in,
                              void* d_out, int out_size, void* d_ws, size_t ws_size,
                              hipStream_t stream) {
  const float* x        = (const float*)d_in[0];
  const int*   edge_src = (const int*)d_in[1];
  const int*   edge_dst = (const int*)d_in[2];
  const float* edge_w   = (const float*)d_in[3];
  const float* w0       = (const float*)d_in[4];
  const float* b0       = (const float*)d_in[5];
  const float* conv_w   = (const float*)d_in[6];
  const float* w1       = (const float*)d_in[7];
  const float* b1       = (const float*)d_in[8];
  float* out = (float*)d_out;

  char* ws = (char*)d_ws;
  size_t off = 0;
  auto alloc = [&](size_t bytes) {
    size_t o = off;
    off = (off + bytes + 255) & ~(size_t)255;
    return (void*)(ws + o);
  };
  float* hA  = (float*)alloc((size_t)N_NODES * NHID * 4);
  float* hB  = (float*)alloc((size_t)N_NODES * NHID * 4);
  float* h0  = (float*)alloc((size_t)N_NODES * NHID * 4);
  int*   rp  = (int*)alloc((size_t)(N_NODES + 1) * 4);
  int*   cnt = (int*)alloc((size_t)N_NODES * 4);
  int*   col = (int*)alloc((size_t)N_EDGES * 4);
  float* val = (float*)alloc((size_t)N_EDGES * 4);
  int*   bs  = (int*)alloc((size_t)NB * 4);
  (void)ws_size;

  // ---- CSR build ----
  hipMemsetAsync(cnt, 0, (size_t)N_NODES * 4, stream);
  k_hist<<<(N_EDGES + 255) / 256, 256, 0, stream>>>(edge_dst, cnt);
  k_blocksum<<<NB, 256, 0, stream>>>(cnt, bs);
  k_scan_top<<<1, 64, 0, stream>>>(bs, rp);
  k_scan_write<<<NB, 256, 0, stream>>>(cnt, bs, rp);
  hipMemsetAsync(cnt, 0, (size_t)N_NODES * 4, stream);
  k_fill<<<(N_EDGES + 255) / 256, 256, 0, stream>>>(edge_src, edge_dst, edge_w, rp,
                                                    cnt, col, val);

  // ---- hA = h0 = relu(x@w0 + b0) ----
  dim3 g0((N_NODES + 127) / 128, NHID / 128);
  k_gemm0<<<g0, 256, 0, stream>>>(x, w0, b0, hA, h0);

  // ---- 8 fused GCNII layers (double-buffered h) ----
  for (int i = 0; i < NLAYERS; ++i) {
    float theta = logf(0.5f / (float)(i + 1) + 1.0f);
    const float* hin  = (i & 1) ? hB : hA;
    float*       hout = (i & 1) ? hA : hB;
    const float* cw = conv_w + (size_t)i * NHID * NHID;
    k_layer<<<N_NODES / TM, 128, 0, stream>>>(rp, col, val, hin, h0, cw, hout, theta);
  }

  // ---- head (final h is hA after 8 layers) ----
  k_final<<<(N_NODES + 15) / 16, 256, 0, stream>>>(hA, w1, b1, out);
}

// Round 5
// 5956.475 us; speedup vs baseline: 1.2499x; 1.2499x over previous
//
#include <hip/hip_runtime.h>
#include <math.h>

#define N_NODES 100000
#define N_EDGES 3200000
#define NFEAT 512
#define NHID 256
#define NCLASS 16
#define NLAYERS 8

#define SCAN_CHUNK 1024
#define NB ((N_NODES + SCAN_CHUNK - 1) / SCAN_CHUNK)   // 98

// ---------------- CSR build ----------------
__global__ void k_hist(const int* __restrict__ dst, int* __restrict__ cnt) {
  int i = blockIdx.x * 256 + threadIdx.x;
  if (i < N_EDGES) atomicAdd(&cnt[dst[i]], 1);
}

__global__ void k_blocksum(const int* __restrict__ cnt, int* __restrict__ bs) {
  __shared__ int red[256];
  int b = blockIdx.x, t = threadIdx.x;
  int s = 0;
  int base = b * SCAN_CHUNK;
  for (int j = 0; j < 4; ++j) {
    int i = base + t + j * 256;
    if (i < N_NODES) s += cnt[i];
  }
  red[t] = s;
  __syncthreads();
  for (int off = 128; off > 0; off >>= 1) {
    if (t < off) red[t] += red[t + off];
    __syncthreads();
  }
  if (t == 0) bs[b] = red[0];
}

__global__ void k_scan_top(int* __restrict__ bs, int* __restrict__ rp) {
  if (threadIdx.x == 0) {
    int run = 0;
    for (int b = 0; b < NB; ++b) { int v = bs[b]; bs[b] = run; run += v; }
    rp[N_NODES] = run;
  }
}

__global__ void k_scan_write(const int* __restrict__ cnt, const int* __restrict__ bs,
                             int* __restrict__ rp) {
  __shared__ int tot[256];
  int b = blockIdx.x, t = threadIdx.x;
  int base = b * SCAN_CHUNK + t * 4;
  int v0 = 0, v1 = 0, v2 = 0, v3 = 0;
  if (base + 0 < N_NODES) v0 = cnt[base + 0];
  if (base + 1 < N_NODES) v1 = cnt[base + 1];
  if (base + 2 < N_NODES) v2 = cnt[base + 2];
  if (base + 3 < N_NODES) v3 = cnt[base + 3];
  int tsum = v0 + v1 + v2 + v3;
  tot[t] = tsum;
  __syncthreads();
  for (int off = 1; off < 256; off <<= 1) {
    int v = 0;
    if (t >= off) v = tot[t - off];
    __syncthreads();
    if (t >= off) tot[t] += v;
    __syncthreads();
  }
  int excl = tot[t] - tsum + bs[b];
  if (base + 0 < N_NODES) rp[base + 0] = excl;
  if (base + 1 < N_NODES) rp[base + 1] = excl + v0;
  if (base + 2 < N_NODES) rp[base + 2] = excl + v0 + v1;
  if (base + 3 < N_NODES) rp[base + 3] = excl + v0 + v1 + v2;
}

__global__ void k_fill(const int* __restrict__ src, const int* __restrict__ dst,
                       const float* __restrict__ w, const int* __restrict__ rp,
                       int* __restrict__ fill, int* __restrict__ col,
                       float* __restrict__ val) {
  int i = blockIdx.x * 256 + threadIdx.x;
  if (i < N_EDGES) {
    int d = dst[i];
    int pos = rp[d] + atomicAdd(&fill[d], 1);
    col[pos] = src[i];
    val[pos] = w[i];
  }
}

// ---------------- SpMM + fused support, feature-split ----------------
// Feature half [f0, f0+128): per-pass streaming set (h/2 + h0/2 + sup/2 +
// col/val = 179 MB) fits the 256 MB L3 -> gathers hit L3 (round-3 measured
// 146 us/half = 11.2 TB/s effective; round-4 fusion broke this, reverted).
// One wave per dst node; lane owns one float2.
__global__ __launch_bounds__(256)
void k_spmm_half(const int* __restrict__ rp, const int* __restrict__ col,
                 const float* __restrict__ val, const float* __restrict__ h,
                 const float* __restrict__ h0, float* __restrict__ sup, int f0) {
  int wave = threadIdx.x >> 6;
  int lane = threadIdx.x & 63;
  int node = blockIdx.x * 4 + wave;
  if (node >= N_NODES) return;
  int e0 = rp[node], e1 = rp[node + 1];
  const float2* __restrict__ hv = (const float2*)h;  // row stride 128 float2
  int fo = (f0 >> 1) + lane;

  float2 a0 = make_float2(0.f, 0.f);
  float2 a1 = make_float2(0.f, 0.f);
  float2 a2 = make_float2(0.f, 0.f);
  float2 a3 = make_float2(0.f, 0.f);

  int e = e0;
  for (; e + 4 <= e1; e += 4) {
    int s0 = col[e], s1 = col[e + 1], s2 = col[e + 2], s3 = col[e + 3];
    float w0 = val[e], w1 = val[e + 1], w2 = val[e + 2], w3 = val[e + 3];
    float2 v0 = hv[(size_t)s0 * 128 + fo];
    float2 v1 = hv[(size_t)s1 * 128 + fo];
    float2 v2 = hv[(size_t)s2 * 128 + fo];
    float2 v3 = hv[(size_t)s3 * 128 + fo];
    a0.x += w0 * v0.x; a0.y += w0 * v0.y;
    a1.x += w1 * v1.x; a1.y += w1 * v1.y;
    a2.x += w2 * v2.x; a2.y += w2 * v2.y;
    a3.x += w3 * v3.x; a3.y += w3 * v3.y;
  }
  for (; e < e1; ++e) {
    int s0 = col[e];
    float w0 = val[e];
    float2 v0 = hv[(size_t)s0 * 128 + fo];
    a0.x += w0 * v0.x; a0.y += w0 * v0.y;
  }

  float2 acc;
  acc.x = (a0.x + a1.x) + (a2.x + a3.x);
  acc.y = (a0.y + a1.y) + (a2.y + a3.y);

  float2 z = ((const float2*)h0)[(size_t)node * 128 + fo];
  float2 o;
  o.x = 0.9f * acc.x + 0.1f * z.x;
  o.y = 0.9f * acc.y + 0.1f * z.y;
  ((float2*)sup)[(size_t)node * 128 + fo] = o;
}

// ---------------- GEMM, 128x128 tile, BK=16, 8x8 micro-tile ----------------
// Conflict-free LDS reads: b-cols split as {tx*4, 64+tx*4} -> 16 lanes x 16B
// contiguous = 2-way bank alias = free (round-3 tx*8 layout: 3.5e7 conflicts).
// a-reads broadcast (4 distinct addrs/wave). Epilogue float4-vectorized.
// MODE 0: out1 = out2 = relu(A@W + bias)                  (A = x, K = 512)
// MODE 1: out1 = relu(theta*(A@W) + (1-theta)*A + hin)    (A = sup, K = 256)
template <int MODE>
__global__ __launch_bounds__(256)
void k_gemm(const float* __restrict__ A, const float* __restrict__ W, int K,
            const float* __restrict__ bias, const float* __restrict__ hin,
            float* __restrict__ out1, float* __restrict__ out2, float theta) {
  __shared__ float As[16][128];
  __shared__ float Bs[16][128];
  int bm = blockIdx.x * 128, bn = blockIdx.y * 128;
  int tid = threadIdx.x;
  int tx = tid & 15, ty = tid >> 4;
  float acc[8][8];
#pragma unroll
  for (int i = 0; i < 8; ++i)
#pragma unroll
    for (int j = 0; j < 8; ++j) acc[i][j] = 0.f;

  for (int kc = 0; kc < K; kc += 16) {
    // stage A tile (transposed into As[k][m])
#pragma unroll
    for (int it = 0; it < 2; ++it) {
      int idx = tid + it * 256;        // 0..511
      int m = idx >> 2, q = (idx & 3) * 4;
      int gm = bm + m;
      float4 f = make_float4(0.f, 0.f, 0.f, 0.f);
      if (gm < N_NODES) f = *(const float4*)&A[(size_t)gm * K + kc + q];
      As[q + 0][m] = f.x; As[q + 1][m] = f.y; As[q + 2][m] = f.z; As[q + 3][m] = f.w;
    }
    // stage B tile (row-major copy)
#pragma unroll
    for (int it = 0; it < 2; ++it) {
      int idx = tid + it * 256;        // 0..511
      int kk = idx >> 5, nq = (idx & 31) * 4;
      *(float4*)&Bs[kk][nq] = *(const float4*)&W[(size_t)(kc + kk) * NHID + bn + nq];
    }
    __syncthreads();
#pragma unroll
    for (int k = 0; k < 16; ++k) {
      float a[8], b[8];
      *(float4*)&a[0] = *(const float4*)&As[k][ty * 8];
      *(float4*)&a[4] = *(const float4*)&As[k][ty * 8 + 4];
      *(float4*)&b[0] = *(const float4*)&Bs[k][tx * 4];
      *(float4*)&b[4] = *(const float4*)&Bs[k][tx * 4 + 64];
#pragma unroll
      for (int i = 0; i < 8; ++i)
#pragma unroll
        for (int j = 0; j < 8; ++j) acc[i][j] += a[i] * b[j];
    }
    __syncthreads();
  }

  // epilogue: cols c0 = bn+tx*4 (j 0..3), c1 = bn+64+tx*4 (j 4..7)
  int c0 = bn + tx * 4, c1 = bn + 64 + tx * 4;
#pragma unroll
  for (int i = 0; i < 8; ++i) {
    int gm = bm + ty * 8 + i;
    if (gm >= N_NODES) continue;
    size_t r0 = (size_t)gm * NHID + c0;
    size_t r1 = (size_t)gm * NHID + c1;
    if (MODE == 0) {
      float4 bb0 = *(const float4*)&bias[c0];
      float4 bb1 = *(const float4*)&bias[c1];
      float4 o0, o1;
      o0.x = fmaxf(acc[i][0] + bb0.x, 0.f);
      o0.y = fmaxf(acc[i][1] + bb0.y, 0.f);
      o0.z = fmaxf(acc[i][2] + bb0.z, 0.f);
      o0.w = fmaxf(acc[i][3] + bb0.w, 0.f);
      o1.x = fmaxf(acc[i][4] + bb1.x, 0.f);
      o1.y = fmaxf(acc[i][5] + bb1.y, 0.f);
      o1.z = fmaxf(acc[i][6] + bb1.z, 0.f);
      o1.w = fmaxf(acc[i][7] + bb1.w, 0.f);
      *(float4*)&out1[r0] = o0;
      *(float4*)&out1[r1] = o1;
      *(float4*)&out2[r0] = o0;
      *(float4*)&out2[r1] = o1;
    } else {
      float omt = 1.f - theta;
      float4 s0 = *(const float4*)&A[r0];
      float4 s1 = *(const float4*)&A[r1];
      float4 h0v = *(const float4*)&hin[r0];
      float4 h1v = *(const float4*)&hin[r1];
      float4 o0, o1;
      o0.x = fmaxf(theta * acc[i][0] + omt * s0.x + h0v.x, 0.f);
      o0.y = fmaxf(theta * acc[i][1] + omt * s0.y + h0v.y, 0.f);
      o0.z = fmaxf(theta * acc[i][2] + omt * s0.z + h0v.z, 0.f);
      o0.w = fmaxf(theta * acc[i][3] + omt * s0.w + h0v.w, 0.f);
      o1.x = fmaxf(theta * acc[i][4] + omt * s1.x + h1v.x, 0.f);
      o1.y = fmaxf(theta * acc[i][5] + omt * s1.y + h1v.y, 0.f);
      o1.z = fmaxf(theta * acc[i][6] + omt * s1.z + h1v.z, 0.f);
      o1.w = fmaxf(theta * acc[i][7] + omt * s1.w + h1v.w, 0.f);
      *(float4*)&out1[r0] = o0;
      *(float4*)&out1[r1] = o1;
    }
  }
}

// ---------------- head: out = sigmoid(h @ w1 + b1) ----------------
__global__ __launch_bounds__(256)
void k_final(const float* __restrict__ h, const float* __restrict__ w1,
             const float* __restrict__ b1, float* __restrict__ out) {
  __shared__ float ws[NHID * NCLASS];
  int t = threadIdx.x;
  for (int i = t; i < NHID * NCLASS; i += 256) ws[i] = w1[i];
  __syncthreads();
  int node = blockIdx.x * 16 + (t >> 4);
  int c = t & 15;
  if (node >= N_NODES) return;
  float acc = b1[c];
  const float* hr = &h[(size_t)node * NHID];
  for (int k = 0; k < NHID; k += 4) {
    float4 hv = *(const float4*)&hr[k];
    acc += hv.x * ws[(k + 0) * NCLASS + c];
    acc += hv.y * ws[(k + 1) * NCLASS + c];
    acc += hv.z * ws[(k + 2) * NCLASS + c];
    acc += hv.w * ws[(k + 3) * NCLASS + c];
  }
  out[(size_t)node * NCLASS + c] = 1.f / (1.f + __expf(-acc));
}

// ---------------- host ----------------
extern "C" void kernel_launch(void* const* d_in, const int* in_sizes, int n_in,
                              void* d_out, int out_size, void* d_ws, size_t ws_size,
                              hipStream_t stream) {
  const float* x        = (const float*)d_in[0];
  const int*   edge_src = (const int*)d_in[1];
  const int*   edge_dst = (const int*)d_in[2];
  const float* edge_w   = (const float*)d_in[3];
  const float* w0       = (const float*)d_in[4];
  const float* b0       = (const float*)d_in[5];
  const float* conv_w   = (const float*)d_in[6];
  const float* w1       = (const float*)d_in[7];
  const float* b1       = (const float*)d_in[8];
  float* out = (float*)d_out;

  char* ws = (char*)d_ws;
  size_t off = 0;
  auto alloc = [&](size_t bytes) {
    size_t o = off;
    off = (off + bytes + 255) & ~(size_t)255;
    return (void*)(ws + o);
  };
  float* h   = (float*)alloc((size_t)N_NODES * NHID * 4);
  float* h0  = (float*)alloc((size_t)N_NODES * NHID * 4);
  float* sup = (float*)alloc((size_t)N_NODES * NHID * 4);
  int*   rp  = (int*)alloc((size_t)(N_NODES + 1) * 4);
  int*   cnt = (int*)alloc((size_t)N_NODES * 4);
  int*   col = (int*)alloc((size_t)N_EDGES * 4);
  float* val = (float*)alloc((size_t)N_EDGES * 4);
  int*   bs  = (int*)alloc((size_t)NB * 4);
  (void)ws_size;

  // ---- CSR build ----
  hipMemsetAsync(cnt, 0, (size_t)N_NODES * 4, stream);
  k_hist<<<(N_EDGES + 255) / 256, 256, 0, stream>>>(edge_dst, cnt);
  k_blocksum<<<NB, 256, 0, stream>>>(cnt, bs);
  k_scan_top<<<1, 64, 0, stream>>>(bs, rp);
  k_scan_write<<<NB, 256, 0, stream>>>(cnt, bs, rp);
  hipMemsetAsync(cnt, 0, (size_t)N_NODES * 4, stream);
  k_fill<<<(N_EDGES + 255) / 256, 256, 0, stream>>>(edge_src, edge_dst, edge_w, rp,
                                                    cnt, col, val);

  // ---- h = relu(x@w0 + b0); h0 = h ----
  dim3 g0((N_NODES + 127) / 128, NHID / 128);
  k_gemm<0><<<g0, 256, 0, stream>>>(x, w0, NFEAT, b0, nullptr, h, h0, 0.f);

  // ---- 8 GCNII layers ----
  for (int i = 0; i < NLAYERS; ++i) {
    float theta = logf(0.5f / (float)(i + 1) + 1.0f);
    k_spmm_half<<<(N_NODES + 3) / 4, 256, 0, stream>>>(rp, col, val, h, h0, sup, 0);
    k_spmm_half<<<(N_NODES + 3) / 4, 256, 0, stream>>>(rp, col, val, h, h0, sup, 128);
    const float* cw = conv_w + (size_t)i * NHID * NHID;
    k_gemm<1><<<g0, 256, 0, stream>>>(sup, cw, NHID, nullptr, h, h, nullptr, theta);
  }

  // ---- head ----
  k_final<<<(N_NODES + 15) / 16, 256, 0, stream>>>(h, w1, b1, out);
}